// Round 1
// baseline (386.118 us; speedup 1.0000x reference)
//
#include <hip/hip_runtime.h>
#include <cstdint>

#define TOPK 2000
#define NMS_THR 0.5f
#define NCLS 21
#define HSHIFT 14
#define HBINS (1u << 18)
#define CAND_CAP 4096

typedef unsigned long long u64;
typedef unsigned int u32;

// IoU exactly as reference get_iou: lt=max, rb=min, wh=clip(rb-lt,0),
// inter=wh0*wh1, iou = inter/(area1+area2-inter). contract(off) to avoid
// fma reassociation vs numpy.
__device__ __forceinline__ float iou_pair(float ax1, float ay1, float ax2, float ay2, float aarea,
                                          float bx1, float by1, float bx2, float by2, float barea) {
#pragma clang fp contract(off)
    float ltx = fmaxf(ax1, bx1), lty = fmaxf(ay1, by1);
    float rbx = fminf(ax2, bx2), rby = fminf(ay2, by2);
    float wx = fmaxf(rbx - ltx, 0.f), wy = fmaxf(rby - lty, 0.f);
    float inter = wx * wy;
    return inter / (aarea + barea - inter);
}

__global__ void k_zero(u32* __restrict__ hist, u32* __restrict__ meta) {
    int i = blockIdx.x * 256 + threadIdx.x;
    ((uint4*)hist)[i] = make_uint4(0u, 0u, 0u, 0u);  // grid sized so i*4 < HBINS
    if (i < 64) meta[i] = 0u;
}

// Per-proposal: softmax score+cls, decode selected-class box (clamped),
// score bits + histogram, GT IoU argmax, encode reg targets -> out rows 2000+.
__global__ __launch_bounds__(256) void k_main(
    const float* __restrict__ prop, const float* __restrict__ btp,
    const float* __restrict__ cls, const float* __restrict__ gt,
    const int* __restrict__ hptr, const int* __restrict__ wptr,
    float* __restrict__ out, float4* __restrict__ box_per,
    u32* __restrict__ score_bits, u32* __restrict__ hist,
    int N, int G) {
#pragma clang fp contract(off)
    __shared__ float4 sgt[256];
    __shared__ float sga[256];
    __shared__ float scls[256 * NCLS];
    int tid = threadIdx.x;
    for (int g = tid; g < G; g += 256) {
        float4 gb = ((const float4*)gt)[g];
        sgt[g] = gb;
        sga[g] = (gb.z - gb.x) * (gb.w - gb.y);
    }
    // stage this block's cls_scores rows into LDS (coalesced)
    size_t base = (size_t)blockIdx.x * 256 * NCLS;
    size_t total = (size_t)N * NCLS;
    int cnt = (int)((total > base) ? ((total - base > (size_t)(256 * NCLS)) ? (size_t)(256 * NCLS)
                                                                            : (total - base))
                                   : (size_t)0);
    if (cnt == 256 * NCLS) {
        const float4* src = (const float4*)(cls + base);
        for (int u = tid; u < 256 * NCLS / 4; u += 256) ((float4*)scls)[u] = src[u];
    } else {
        for (int u = tid; u < cnt; u += 256) scls[u] = cls[base + u];
    }
    __syncthreads();

    int i = blockIdx.x * 256 + tid;
    if (i >= N) return;

    float W = (float)wptr[0], H = (float)hptr[0];
    float4 p = ((const float4*)prop)[i];
    float pw = p.z - p.x, ph = p.w - p.y;
    float pcx = p.x + 0.5f * pw, pcy = p.y + 0.5f * ph;

    // softmax, jax.nn.softmax semantics: max-subtract, exp, seq-sum, divide
    const float* s = &scls[tid * NCLS];
    float m = s[0];
#pragma unroll
    for (int c = 1; c < NCLS; ++c) m = fmaxf(m, s[c]);
    float e[NCLS];
    float Z = 0.f;
#pragma unroll
    for (int c = 0; c < NCLS; ++c) {
        e[c] = expf(s[c] - m);
        Z += e[c];
    }
    // fg max prob + argmax (first max wins, IEEE division like reference)
    float best = -1.f;
    int bc = 1;
#pragma unroll
    for (int c = 1; c < NCLS; ++c) {
        float pr = e[c] / Z;
        if (pr > best) { best = pr; bc = c; }
    }

    // decode box for selected class, clamp to image
    float4 t = ((const float4*)btp)[(size_t)i * NCLS + bc];
    float qcx = t.x * pw + pcx, qcy = t.y * ph + pcy;
    float qw = expf(t.z) * pw, qh = expf(t.w) * ph;
    float bx1 = fminf(fmaxf(qcx - 0.5f * qw, 0.f), W);
    float by1 = fminf(fmaxf(qcy - 0.5f * qh, 0.f), H);
    float bx2 = fminf(fmaxf(qcx + 0.5f * qw, 0.f), W);
    float by2 = fminf(fmaxf(qcy + 0.5f * qh, 0.f), H);
    box_per[i] = make_float4(bx1, by1, bx2, by2);

    u32 b = __float_as_uint(best);  // score>0 -> uint order == float order
    score_bits[i] = b;
    atomicAdd(&hist[b >> HSHIFT], 1u);

    // argmax over GT IoU (first max wins)
    float parea = pw * ph;
    float bestiou = -1.f;
    int bi = 0;
    for (int g = 0; g < G; ++g) {
        float4 gb = sgt[g];
        float v = iou_pair(gb.x, gb.y, gb.z, gb.w, sga[g], p.x, p.y, p.z, p.w, parea);
        if (v > bestiou) { bestiou = v; bi = g; }
    }
    float4 mg = sgt[bi];
    float gw = mg.z - mg.x, gh = mg.w - mg.y;
    float gcx = mg.x + 0.5f * gw, gcy = mg.y + 0.5f * gh;
    float4 rt = make_float4((gcx - pcx) / pw, (gcy - pcy) / ph, logf(gw / pw), logf(gh / ph));
    ((float4*)out)[TOPK + i] = rt;
}

// Find smallest bin B with count(bins >= B) >= TOPK. One block.
__global__ __launch_bounds__(1024) void k_scan(const u32* __restrict__ hist, u32* __restrict__ meta) {
    __shared__ u32 S[1024];
    __shared__ u32 sh_tc, sh_E;
    int t = threadIdx.x;
    const int CH = HBINS / 1024;  // 256
    u32 acc = 0;
    size_t b0 = (size_t)t * CH;
    for (int u = 0; u < CH; ++u) acc += hist[b0 + u];
    S[t] = acc;
    __syncthreads();
    for (int off = 1; off < 1024; off <<= 1) {  // inclusive suffix scan
        u32 v = (t + off < 1024) ? S[t + off] : 0u;
        __syncthreads();
        S[t] += v;
        __syncthreads();
    }
    u32 suff = S[t];
    u32 E = suff - acc;  // exclusive suffix (bins above my chunk)
    if (suff >= TOPK && E < TOPK) { sh_tc = (u32)t; sh_E = E; }
    __syncthreads();
    u32 tc = sh_tc, E0 = sh_E;
    u32 h = 0;
    if (t < CH) h = hist[(size_t)tc * CH + t];
    __syncthreads();
    S[t] = (t < CH) ? h : 0u;
    __syncthreads();
    for (int off = 1; off < CH; off <<= 1) {
        u32 v = (t + off < 1024) ? S[t + off] : 0u;
        __syncthreads();
        S[t] += v;
        __syncthreads();
    }
    if (t < CH) {
        u32 tot = E0 + S[t];
        if (tot >= TOPK && (tot - h) < TOPK) meta[0] = tc * (u32)CH + (u32)t;
    }
}

__global__ __launch_bounds__(256) void k_compact(const u32* __restrict__ score_bits,
                                                 const u32* __restrict__ meta, u32* __restrict__ cnt,
                                                 u64* __restrict__ keys, int N) {
    int i = blockIdx.x * 256 + threadIdx.x;
    if (i >= N) return;
    u32 b = score_bits[i];
    if ((b >> HSHIFT) >= meta[0]) {
        u32 pos = atomicAdd(cnt, 1u);
        if (pos < CAND_CAP) keys[pos] = ((u64)b << 32) | (u32)(~(u32)i);
    }
}

// One-block bitonic sort of up to 4096 keys, descending -> exact lax.top_k order.
__global__ __launch_bounds__(1024) void k_sort(const u64* __restrict__ keys,
                                               const u32* __restrict__ meta,
                                               const float4* __restrict__ box_per,
                                               float4* __restrict__ topbox) {
    __shared__ u64 sk[CAND_CAP];
    int t = threadIdx.x;
    u32 M = meta[1];
    if (M > CAND_CAP) M = CAND_CAP;
    for (int u = t; u < CAND_CAP; u += 1024) sk[u] = (u < (int)M) ? keys[u] : 0ull;
    for (int kk = 2; kk <= CAND_CAP; kk <<= 1)
        for (int j = kk >> 1; j > 0; j >>= 1) {
            __syncthreads();
            for (int idx = t; idx < CAND_CAP; idx += 1024) {
                int ix = idx ^ j;
                if (ix > idx) {
                    u64 a = sk[idx], b = sk[ix];
                    bool up = (idx & kk) == 0;
                    if (up ? (a < b) : (a > b)) { sk[idx] = b; sk[ix] = a; }
                }
            }
        }
    __syncthreads();
    for (int r = t; r < TOPK; r += 1024) {
        u32 idx = ~(u32)(sk[r] & 0xffffffffull);
        topbox[r] = box_per[idx];
    }
}

// Suppression bitmask: mask[i][w] bit jj set iff j=w*64+jj > i and iou>thr.
__global__ __launch_bounds__(256) void k_mask(const float4* __restrict__ topbox,
                                              u64* __restrict__ mask) {
#pragma clang fp contract(off)
    int gid = blockIdx.x * 256 + threadIdx.x;
    if (gid >= TOPK * 32) return;
    int i = gid >> 5, w = gid & 31;
    float4 a = topbox[i];
    float aarea = (a.z - a.x) * (a.w - a.y);
    u64 m = 0;
    int j0 = w << 6;
    for (int jj = 0; jj < 64; ++jj) {
        int j = j0 + jj;
        if (j < TOPK && j > i) {
            float4 b = topbox[j];
            float barea = (b.z - b.x) * (b.w - b.y);
            float v = iou_pair(a.x, a.y, a.z, a.w, aarea, b.x, b.y, b.z, b.w, barea);
            if (v > NMS_THR) m |= (1ull << jj);
        }
    }
    mask[(size_t)i * 32 + w] = m;
}

// Sequential greedy NMS over precomputed masks; chunked 64 rows; writes out rows 0..1999.
__global__ __launch_bounds__(1024) void k_nms(const u64* __restrict__ mask,
                                              const float4* __restrict__ topbox,
                                              float* __restrict__ out) {
    __shared__ u64 cm[64][33];  // +1 pad: avoid 32-way bank conflict on column reads
    __shared__ u64 removed[32];
    int t = threadIdx.x;
    if (t < 32) removed[t] = 0ull;
    for (int c = 0; c < 32; ++c) {
        __syncthreads();
        for (int u = t; u < 2048; u += 1024) {
            int l = u >> 5, w = u & 31;
            int i = c * 64 + l;
            cm[l][w] = (i < TOPK) ? mask[(size_t)i * 32 + w] : 0ull;
        }
        __syncthreads();
        if (t == 0) {  // serial intra-word dependency, pure registers
            u64 rw = removed[c];
#pragma unroll
            for (int half = 0; half < 2; ++half) {
                u64 mv[32];
#pragma unroll
                for (int l = 0; l < 32; ++l) mv[l] = cm[half * 32 + l][c];
#pragma unroll
                for (int l = 0; l < 32; ++l) {
                    int bit = half * 32 + l;
                    if (!((rw >> bit) & 1ull)) rw |= mv[l];
                }
            }
            removed[c] = rw;
        }
        __syncthreads();
        int g = t >> 5, sl = t & 31;
        if (g > c) {  // parallel cross-word suppression by finalized chunk
            u64 rw = removed[c];
            u64 acc2 = 0;
            for (int l = sl; l < 64; l += 32)
                if (!((rw >> l) & 1ull)) acc2 |= cm[l][g];
            acc2 |= __shfl_xor(acc2, 16);
            acc2 |= __shfl_xor(acc2, 8);
            acc2 |= __shfl_xor(acc2, 4);
            acc2 |= __shfl_xor(acc2, 2);
            acc2 |= __shfl_xor(acc2, 1);
            if (sl == 0) removed[g] |= acc2;
        }
    }
    __syncthreads();
    for (int r = t; r < TOPK; r += 1024) {
        bool sup = (removed[r >> 6] >> (r & 63)) & 1ull;
        float4 b = topbox[r];
        float4 o = sup ? make_float4(0.f, 0.f, 0.f, 0.f) : b;
        ((float4*)out)[r] = o;
    }
}

extern "C" void kernel_launch(void* const* d_in, const int* in_sizes, int n_in,
                              void* d_out, int out_size, void* d_ws, size_t ws_size,
                              hipStream_t stream) {
    const float* prop = (const float*)d_in[0];
    const float* btp = (const float*)d_in[1];
    const float* cls = (const float*)d_in[2];
    const float* gt = (const float*)d_in[3];
    const int* hptr = (const int*)d_in[4];
    const int* wptr = (const int*)d_in[5];
    float* out = (float*)d_out;
    int N = in_sizes[0] / 4;
    int G = in_sizes[3] / 4;
    if (G > 256) G = 256;

    char* ws = (char*)d_ws;
    size_t o = 0;
    u32* hist = (u32*)(ws + o);      o += (size_t)HBINS * 4;
    u32* meta = (u32*)(ws + o);      o += 256;
    u32* score_bits = (u32*)(ws + o); o += (((size_t)N * 4 + 255) & ~(size_t)255);
    u64* keys = (u64*)(ws + o);      o += (size_t)CAND_CAP * 8;
    float4* box_per = (float4*)(ws + o); o += (size_t)N * 16;
    float4* topbox = (float4*)(ws + o);  o += (size_t)TOPK * 16;
    u64* mask = (u64*)(ws + o);      o += (size_t)TOPK * 32 * 8;
    (void)o; (void)ws_size; (void)n_in; (void)out_size;

    int nb = (N + 255) / 256;
    k_zero<<<HBINS / 4 / 256, 256, 0, stream>>>(hist, meta);
    k_main<<<nb, 256, 0, stream>>>(prop, btp, cls, gt, hptr, wptr, out, box_per, score_bits,
                                   hist, N, G);
    k_scan<<<1, 1024, 0, stream>>>(hist, meta);
    k_compact<<<nb, 256, 0, stream>>>(score_bits, meta, meta + 1, keys, N);
    k_sort<<<1, 1024, 0, stream>>>(keys, meta, box_per, topbox);
    k_mask<<<(TOPK * 32 + 255) / 256, 256, 0, stream>>>(topbox, mask);
    k_nms<<<1, 1024, 0, stream>>>(mask, topbox, out);
}